// Round 18
// baseline (185.438 us; speedup 1.0000x reference)
//
#include <hip/hip_runtime.h>
#include <hip/hip_fp16.h>

typedef _Float16 half8_t __attribute__((ext_vector_type(8)));
typedef float float4_t __attribute__((ext_vector_type(4)));

__device__ __forceinline__ float2 h2f2(unsigned int u) {
  return __half22float2(__builtin_bit_cast(__half2, u));
}
__device__ __forceinline__ unsigned int f2h2(float a, float b) {
  return __builtin_bit_cast(unsigned int, __floats2half2_rn(a, b));
}

#if __has_builtin(__builtin_amdgcn_fdot2)
typedef _Float16 h2v __attribute__((ext_vector_type(2)));
__device__ __forceinline__ float fdot2(unsigned int a, unsigned int b, float c) {
  return __builtin_amdgcn_fdot2(__builtin_bit_cast(h2v, a),
                                __builtin_bit_cast(h2v, b), c, false);
}
#else
__device__ __forceinline__ float fdot2(unsigned int a, unsigned int b, float c) {
  float2 fa = h2f2(a), fb = h2f2(b);
  return fmaf(fa.y, fb.y, fmaf(fa.x, fb.x, c));
}
#endif

// ---------------- K0: fused LN stats + LN apply -> xn (single HBM x read) --
// grid (513, 2): x<512 main blocks (16 px-pairs each; 1024 total = 4/CU);
// x==512 && bt==0 packs weights + zeros Sacc/Nacc.
// Pass 1: thread (t = tid>>4, jl = tid&15) -> stats for pair jp0+jl, frame t.
// Pass 2: thread (cig = tid>>4, p = tid&15) -> 4 ci x pair p (64 B store/ci);
//         x re-read is L3-hot (x fits in 256 MB Infinity Cache).
// xn: [bc][px][8 words], word tp = (t=2tp, t=2tp+1).
__global__ __launch_bounds__(256) void k_statsxn(
    const float2* __restrict__ x2, const float* __restrict__ lnw,
    const float* __restrict__ lnb, unsigned int* __restrict__ xnw,
    const float* __restrict__ qkvw, const float* __restrict__ dww,
    const float* __restrict__ projw, unsigned int* __restrict__ qkvpk,
    unsigned int* __restrict__ dwpk, unsigned int* __restrict__ projpk,
    float* __restrict__ Sacc) {
  int bt = blockIdx.y;
  if (blockIdx.x >= 512) {
    if (bt == 0) {
      for (int t = threadIdx.x; t < 2648; t += 256) {
        if (t < 2048) {
          int o = t >> 5, c2 = t & 31;
          projpk[t] = f2h2(projw[(o << 6) + 2 * c2], projw[(o << 6) + 2 * c2 + 1]);
        } else if (t < 2432) {
          int i = t - 2048;
          int ch = i >> 3, tp = i & 7;
          qkvpk[i] = f2h2(qkvw[(ch << 4) + 2 * tp], qkvw[(ch << 4) + 2 * tp + 1]);
        } else {
          int i = t - 2432;
          int pl = i / 9, k = i - pl * 9;
          dwpk[i] = f2h2(dww[18 * pl + k], dww[18 * pl + 9 + k]);
        }
      }
      for (int t = threadIdx.x; t < 12288; t += 256) Sacc[t] = 0.f;  // Sacc+Nacc
    }
    return;
  }
  __shared__ float2 st[16][32];   // [t][pair*2 + px-half], 4 KB
  int tid = threadIdx.x;
  int jp0 = blockIdx.x << 4;      // first px-pair of this block

  // ---- pass 1: per-frame stats, 1 pair/thread (k_stats-proven pattern) ----
  {
    int t = tid >> 4, jl = tid & 15;
    const float2* xt = x2 + ((size_t)(bt * 16 + t) << 19) + jp0 + jl;
    float s0 = 0.f, q0 = 0.f, s1 = 0.f, q1 = 0.f;
#pragma unroll 8
    for (int ci = 0; ci < 64; ++ci) {
      float2 v = xt[(size_t)ci << 13];
      s0 += v.x; q0 = fmaf(v.x, v.x, q0);
      s1 += v.y; q1 = fmaf(v.y, v.y, q1);
    }
    float mu0 = s0 * (1.f / 64.f), mu1 = s1 * (1.f / 64.f);
    float r0 = rsqrtf(fmaf(-mu0, mu0, q0 * (1.f / 64.f)) + 1e-5f);
    float r1 = rsqrtf(fmaf(-mu1, mu1, q1 * (1.f / 64.f)) + 1e-5f);
    st[t][jl * 2 + 0] = make_float2(mu0, r0);
    st[t][jl * 2 + 1] = make_float2(mu1, r1);
  }
  __syncthreads();

  // ---- pass 2: LN + t-pair pack + 64 B stores; x re-read L3-hot ----
  {
    int cig = tid >> 4, p = tid & 15;
    int jp = jp0 + p;
#pragma unroll
    for (int cc = 0; cc < 4; ++cc) {
      int ci = cig * 4 + cc;
      float lw = lnw[ci], lb = lnb[ci];
      const float2* xc = x2 + ((size_t)ci << 13) + jp + ((size_t)(bt * 16) << 19);
      unsigned int w0[8], w1[8];
#pragma unroll
      for (int tp = 0; tp < 8; ++tp) {
        float2 va = xc[((size_t)(2 * tp) << 19)];
        float2 vb = xc[((size_t)(2 * tp + 1) << 19)];
        float2 sa0 = st[2 * tp][p * 2 + 0];
        float2 sb0 = st[2 * tp + 1][p * 2 + 0];
        float2 sa1 = st[2 * tp][p * 2 + 1];
        float2 sb1 = st[2 * tp + 1][p * 2 + 1];
        w0[tp] = f2h2(fmaf((va.x - sa0.x) * sa0.y, lw, lb),
                      fmaf((vb.x - sb0.x) * sb0.y, lw, lb));
        w1[tp] = f2h2(fmaf((va.y - sa1.x) * sa1.y, lw, lb),
                      fmaf((vb.y - sb1.x) * sb1.y, lw, lb));
      }
      unsigned int* dst =
          xnw + ((size_t)((bt << 6) + ci) << 17) + (size_t)(2 * jp) * 8;
      *reinterpret_cast<uint4*>(dst + 0) = make_uint4(w0[0], w0[1], w0[2], w0[3]);
      *reinterpret_cast<uint4*>(dst + 4) = make_uint4(w0[4], w0[5], w0[6], w0[7]);
      *reinterpret_cast<uint4*>(dst + 8) = make_uint4(w1[0], w1[1], w1[2], w1[3]);
      *reinterpret_cast<uint4*>(dst + 12) = make_uint4(w1[4], w1[5], w1[6], w1[7]);
    }
  }
}

// ---------------- K1: global-fed MFMA 1x1 + dw3x3 + attn partials + v -----
// (r16 verbatim — proven geometry)
__global__ __launch_bounds__(256) void k_fused(
    const unsigned int* __restrict__ xnw, const unsigned int* __restrict__ qkvpk,
    const unsigned int* __restrict__ dwpk, unsigned int* __restrict__ vbuf,
    float* __restrict__ Sacc, float* __restrict__ Nacc) {
  __shared__ unsigned int pre[8 * 612];   // 19.6 KB
  __shared__ unsigned int qk[16 * 258];   // 16.5 KB
  int tid = threadIdx.x;
  int bc = blockIdx.y;
  int tx0 = (blockIdx.x & 3) << 5;
  int ty0 = (blockIdx.x >> 2) << 4;
  int lane15 = tid & 15;
  int kg = (tid >> 4) & 3;
  int wv = tid >> 6;
  int iy = tid >> 4, jx = tid & 15;
  int dwbase = iy * 34 + 2 * jx;

  uint4 bfr[10];
#pragma unroll
  for (int i = 0; i < 10; ++i) {
    int hp = (wv + 4 * i) * 16 + lane15;
    int hy = hp / 34, hx = hp - hy * 34;
    int gy = ty0 + hy - 1, gx = tx0 + hx - 1;
    bool ok = (hp < 612) && ((unsigned)gy < 128u) && ((unsigned)gx < 128u);
    uint4 bw = make_uint4(0, 0, 0, 0);
    if (ok && kg < 2)
      bw = *reinterpret_cast<const uint4*>(
          &xnw[((size_t)bc << 17) + (size_t)((gy << 7) + gx) * 8 + 4 * kg]);
    bfr[i] = bw;
  }

  for (int m = 0; m < 3; ++m) {
    if (m > 0) {
      int pm = m - 1;
      {
        int combo = tid >> 3, pc = tid & 7;
        int hp_ = combo >> 4, cd = combo & 15, cc = cd >> 2, dd = cd & 3;
        const unsigned int* qrow = qk + (4 * hp_ + cc) * 258;
        const unsigned int* krow = qk + (8 + 4 * hp_ + dd) * 258;
        float s = 0.f;
#pragma unroll
        for (int i = 0; i < 16; ++i) {
          uint2 q2 = *reinterpret_cast<const uint2*>(&qrow[2 * pc + (i << 4)]);
          uint2 k2 = *reinterpret_cast<const uint2*>(&krow[2 * pc + (i << 4)]);
          s = fdot2(q2.x, k2.x, s);
          s = fdot2(q2.y, k2.y, s);
        }
        s += __shfl_xor(s, 1); s += __shfl_xor(s, 2); s += __shfl_xor(s, 4);
        if (pc == 0)
          atomicAdd(&Sacc[((bc << 2) + 2 * pm + hp_) * 16 + cc * 4 + dd], s);
      }
      {
        int row = tid >> 4, pc = tid & 15;
        const unsigned int* rp = qk + row * 258;
        float n = 0.f;
#pragma unroll
        for (int i = 0; i < 8; ++i) {
          uint2 v2 = *reinterpret_cast<const uint2*>(&rp[2 * pc + (i << 5)]);
          n = fdot2(v2.x, v2.x, n);
          n = fdot2(v2.y, v2.y, n);
        }
        n += __shfl_xor(n, 1); n += __shfl_xor(n, 2);
        n += __shfl_xor(n, 4); n += __shfl_xor(n, 8);
        if (pc == 0) {
          int g = (row < 8) ? (8 * pm + row) : (16 + 8 * pm + (row - 8));
          atomicAdd(&Nacc[(bc << 5) + g], n);
        }
      }
    }
    {
      int gch = (m < 2)
                    ? ((lane15 < 8) ? (8 * m + lane15) : (16 + 8 * m + (lane15 - 8)))
                    : (32 + lane15);
      uint4 aw = make_uint4(0, 0, 0, 0);
      if (kg < 2) aw = *reinterpret_cast<const uint4*>(&qkvpk[gch * 8 + 4 * kg]);
      half8_t af = __builtin_bit_cast(half8_t, aw);
      float4_t zz = {0.f, 0.f, 0.f, 0.f};
#pragma unroll
      for (int i = 0; i < 10; ++i) {
        int hp = (wv + 4 * i) * 16 + lane15;
        half8_t bf = __builtin_bit_cast(half8_t, bfr[i]);
        float4_t d = __builtin_amdgcn_mfma_f32_16x16x32_f16(af, bf, zz, 0, 0, 0);
        if (hp < 612) {
          pre[(2 * kg) * 612 + hp] = f2h2(d[0], d[1]);
          pre[(2 * kg + 1) * 612 + hp] = f2h2(d[2], d[3]);
        }
      }
    }
    __syncthreads();
    unsigned int vs0[8], vs1[8];
#pragma unroll
    for (int pl = 0; pl < 8; ++pl) {
      int gpl = (m < 2) ? ((pl < 4) ? (4 * m + pl) : (8 + 4 * m + (pl - 4)))
                        : (16 + pl);
      const unsigned int* wp = dwpk + gpl * 9;
      __half2 a0 = __floats2half2_rn(0.f, 0.f), a1 = a0;
      int base = pl * 612 + dwbase;
#pragma unroll
      for (int dy = 0; dy < 3; ++dy) {
        uint2 A = *reinterpret_cast<const uint2*>(&pre[base + dy * 34]);
        uint2 B = *reinterpret_cast<const uint2*>(&pre[base + dy * 34 + 2]);
        __half2 d0 = __builtin_bit_cast(__half2, A.x);
        __half2 d1 = __builtin_bit_cast(__half2, A.y);
        __half2 d2 = __builtin_bit_cast(__half2, B.x);
        __half2 d3 = __builtin_bit_cast(__half2, B.y);
        __half2 w0 = __builtin_bit_cast(__half2, wp[dy * 3 + 0]);
        __half2 w1 = __builtin_bit_cast(__half2, wp[dy * 3 + 1]);
        __half2 w2 = __builtin_bit_cast(__half2, wp[dy * 3 + 2]);
        a0 = __hfma2(w0, d0, a0); a0 = __hfma2(w1, d1, a0); a0 = __hfma2(w2, d2, a0);
        a1 = __hfma2(w0, d1, a1); a1 = __hfma2(w1, d2, a1); a1 = __hfma2(w2, d3, a1);
      }
      unsigned int u0 = __builtin_bit_cast(unsigned int, a0);
      unsigned int u1 = __builtin_bit_cast(unsigned int, a1);
      if (m < 2) {
        qk[(2 * pl) * 258 + tid]     = (u0 & 0xFFFFu) | (u1 << 16);
        qk[(2 * pl + 1) * 258 + tid] = (u0 >> 16) | (u1 & 0xFFFF0000u);
      } else {
        vs0[pl] = u0;
        vs1[pl] = u1;
      }
    }
    if (m < 2) {
      __syncthreads();
    } else {
      int px0 = ((ty0 + iy) << 7) + tx0 + 2 * jx;
#pragma unroll
      for (int hg = 0; hg < 4; ++hg) {
        size_t a = (((size_t)(bc * 4 + hg)) << 15) + (size_t)px0 * 2;
        *reinterpret_cast<uint4*>(&vbuf[a]) =
            make_uint4(vs0[2 * hg], vs0[2 * hg + 1], vs1[2 * hg], vs1[2 * hg + 1]);
      }
    }
  }
}

// ---------------- K2: softmax + out = proj @ (attn . v), c-loop ----------
// (r16 verbatim)
__global__ __launch_bounds__(256) void k_outproj(
    const unsigned int* __restrict__ vbuf, const float* __restrict__ Sacc,
    const float* __restrict__ Nacc, const float* __restrict__ temp,
    const unsigned int* __restrict__ projpk, float* __restrict__ out) {
  __shared__ unsigned int Yl[32 * 260];   // [ci2][px], stride 260
  __shared__ unsigned int attn_l[512];    // [c][ci][2]
  int tid = threadIdx.x;
  int comb = blockIdx.y;                  // bt*4 + hd
  int bt = comb >> 2, hd = comb & 3;
  int lane15 = tid & 15;
  int kg = (tid >> 4) & 3;
  int wv = tid >> 6;

  {  // all 4 c-rows of softmax: c = tid>>6, ci = tid&63
    int c = tid >> 6, ci = tid & 63;
    int b = (bt << 6) + ci;
    float tp = temp[hd];
    float iq = 1.f / fmaxf(sqrtf(Nacc[(b << 5) + (hd << 2) + c]), 1e-12f);
    float l[4];
#pragma unroll
    for (int d = 0; d < 4; ++d) {
      float ik = 1.f / fmaxf(sqrtf(Nacc[(b << 5) + 16 + (hd << 2) + d]), 1e-12f);
      l[d] = Sacc[((b << 2) + hd) * 16 + c * 4 + d] * iq * ik * tp;
    }
    float mx = fmaxf(fmaxf(l[0], l[1]), fmaxf(l[2], l[3]));
    float e0 = expf(l[0] - mx), e1 = expf(l[1] - mx);
    float e2 = expf(l[2] - mx), e3 = expf(l[3] - mx);
    float inv = 1.f / (e0 + e1 + e2 + e3);
    attn_l[c * 128 + 2 * ci] = f2h2(e0 * inv, e1 * inv);
    attn_l[c * 128 + 2 * ci + 1] = f2h2(e2 * inv, e3 * inv);
  }
  __syncthreads();

  half8_t A0[4], A1[4];
#pragma unroll
  for (int ot = 0; ot < 4; ++ot) {
    A0[ot] = __builtin_bit_cast(
        half8_t, *reinterpret_cast<const uint4*>(
                     &projpk[(ot * 16 + lane15) * 32 + kg * 4]));
    A1[ot] = __builtin_bit_cast(
        half8_t, *reinterpret_cast<const uint4*>(
                     &projpk[(ot * 16 + lane15) * 32 + 16 + kg * 4]));
  }
  float4_t zz = {0.f, 0.f, 0.f, 0.f};
  int gpx = (blockIdx.x << 8) + tid;
  size_t vb = (((size_t)(bt * 256 + hd)) << 15) + (size_t)gpx * 2;

  for (int c = 0; c < 4; ++c) {
    {
      const unsigned int* al = attn_l + c * 128;
#pragma unroll
      for (int ci2 = 0; ci2 < 32; ++ci2) {
        uint2 A0v = *reinterpret_cast<const uint2*>(&vbuf[vb + ((size_t)(2 * ci2) << 17)]);
        uint2 A1v = *reinterpret_cast<const uint2*>(&vbuf[vb + ((size_t)(2 * ci2 + 1) << 17)]);
        uint4 aw = *reinterpret_cast<const uint4*>(&al[4 * ci2]);
        float y0 = fdot2(A0v.x, aw.x, fdot2(A0v.y, aw.y, 0.f));
        float y1 = fdot2(A1v.x, aw.z, fdot2(A1v.y, aw.w, 0.f));
        Yl[ci2 * 260 + tid] = f2h2(y0, y1);
      }
    }
    __syncthreads();
    size_t outbase = ((size_t)((bt << 4) + (hd << 2) + c) << 20) + (blockIdx.x << 8);
#pragma unroll
    for (int pt = 0; pt < 4; ++pt) {
      int pxl = wv * 64 + pt * 16 + lane15;
      unsigned int r0 = Yl[(kg * 4 + 0) * 260 + pxl];
      unsigned int r1 = Yl[(kg * 4 + 1) * 260 + pxl];
      unsigned int r2 = Yl[(kg * 4 + 2) * 260 + pxl];
      unsigned int r3 = Yl[(kg * 4 + 3) * 260 + pxl];
      half8_t B0 = __builtin_bit_cast(half8_t, make_uint4(r0, r1, r2, r3));
      unsigned int s0 = Yl[(16 + kg * 4 + 0) * 260 + pxl];
      unsigned int s1 = Yl[(16 + kg * 4 + 1) * 260 + pxl];
      unsigned int s2 = Yl[(16 + kg * 4 + 2) * 260 + pxl];
      unsigned int s3 = Yl[(16 + kg * 4 + 3) * 260 + pxl];
      half8_t B1 = __builtin_bit_cast(half8_t, make_uint4(s0, s1, s2, s3));
#pragma unroll
      for (int ot = 0; ot < 4; ++ot) {
        float4_t d = __builtin_amdgcn_mfma_f32_16x16x32_f16(A0[ot], B0, zz, 0, 0, 0);
        d = __builtin_amdgcn_mfma_f32_16x16x32_f16(A1[ot], B1, d, 0, 0, 0);
        int o0 = ot * 16 + kg * 4;
#pragma unroll
        for (int r = 0; r < 4; ++r)
          out[outbase + ((size_t)(o0 + r) << 14) + pxl] = d[r];
      }
    }
    __syncthreads();
  }
}

extern "C" void kernel_launch(void* const* d_in, const int* in_sizes, int n_in,
                              void* d_out, int out_size, void* d_ws, size_t ws_size,
                              hipStream_t stream) {
  const float* x = (const float*)d_in[0];
  const float* lnw = (const float*)d_in[1];
  const float* lnb = (const float*)d_in[2];
  const float* qkvw = (const float*)d_in[3];
  const float* dww = (const float*)d_in[4];
  const float* projw = (const float*)d_in[5];
  const float* temp = (const float*)d_in[6];
  float* out = (float*)d_out;

  // workspace: xn 64 MiB | vbuf 64 MiB | Sacc | Nacc | packs
  unsigned int* xnw = (unsigned int*)d_ws;
  unsigned int* vbuf = xnw + (67108864ull / 4);
  char* tail = (char*)d_ws + 134217728ull;
  float* Sacc = (float*)tail;                             // 8192 f32
  float* Nacc = Sacc + 8192;                              // 4096 f32
  unsigned int* projpk = (unsigned int*)(Nacc + 4096);    // 2048 u32
  unsigned int* qkvpk = projpk + 2048;                    // 384 u32
  unsigned int* dwpk = qkvpk + 384;                       // 216 u32

  k_statsxn<<<dim3(513, 2), dim3(256), 0, stream>>>(
      (const float2*)x, lnw, lnb, xnw, qkvw, dww, projw, qkvpk, dwpk, projpk,
      Sacc);
  k_fused<<<dim3(32, 128), dim3(256), 0, stream>>>(xnw, qkvpk, dwpk, vbuf, Sacc,
                                                   Nacc);
  k_outproj<<<dim3(64, 8), dim3(256), 0, stream>>>(vbuf, Sacc, Nacc, temp,
                                                   projpk, out);
}

// Round 19
// 179.197 us; speedup vs baseline: 1.0348x; 1.0348x over previous
//
#include <hip/hip_runtime.h>
#include <hip/hip_fp16.h>

typedef _Float16 half8_t __attribute__((ext_vector_type(8)));
typedef float float4_t __attribute__((ext_vector_type(4)));

__device__ __forceinline__ float2 h2f2(unsigned int u) {
  return __half22float2(__builtin_bit_cast(__half2, u));
}
__device__ __forceinline__ unsigned int f2h2(float a, float b) {
  return __builtin_bit_cast(unsigned int, __floats2half2_rn(a, b));
}

#if __has_builtin(__builtin_amdgcn_fdot2)
typedef _Float16 h2v __attribute__((ext_vector_type(2)));
__device__ __forceinline__ float fdot2(unsigned int a, unsigned int b, float c) {
  return __builtin_amdgcn_fdot2(__builtin_bit_cast(h2v, a),
                                __builtin_bit_cast(h2v, b), c, false);
}
#else
__device__ __forceinline__ float fdot2(unsigned int a, unsigned int b, float c) {
  float2 fa = h2f2(a), fb = h2f2(b);
  return fmaf(fa.y, fb.y, fmaf(fa.x, fb.x, c));
}
#endif

// ---------------- K0: LN stats (blocks 0..1023) + pack + zero (block 1024) --
__global__ __launch_bounds__(256) void k_stats(
    const float2* __restrict__ x2, float4* __restrict__ stats4,
    const float* __restrict__ qkvw, const float* __restrict__ dww,
    const float* __restrict__ projw, unsigned int* __restrict__ qkvpk,
    unsigned int* __restrict__ dwpk, unsigned int* __restrict__ projpk,
    float* __restrict__ Sacc) {
  if (blockIdx.x >= 1024) {
    for (int t = threadIdx.x; t < 2648; t += 256) {
      if (t < 2048) {
        int o = t >> 5, c2 = t & 31;
        projpk[t] = f2h2(projw[(o << 6) + 2 * c2], projw[(o << 6) + 2 * c2 + 1]);
      } else if (t < 2432) {
        int i = t - 2048;
        int ch = i >> 3, tp = i & 7;
        qkvpk[i] = f2h2(qkvw[(ch << 4) + 2 * tp], qkvw[(ch << 4) + 2 * tp + 1]);
      } else {
        int i = t - 2432;
        int pl = i / 9, k = i - pl * 9;
        dwpk[i] = f2h2(dww[18 * pl + k], dww[18 * pl + 9 + k]);
      }
    }
    for (int t = threadIdx.x; t < 12288; t += 256) Sacc[t] = 0.f;  // Sacc+Nacc
    return;
  }
  int id = blockIdx.x * 256 + threadIdx.x;   // 32 * 8192
  int bb = id >> 13;
  int jp = id & 8191;
  const float2* xp = x2 + ((size_t)bb << 19) + jp;
  float s0 = 0.f, q0 = 0.f, s1 = 0.f, q1 = 0.f;
#pragma unroll
  for (int ci = 0; ci < 64; ++ci) {
    float2 v = xp[(size_t)ci << 13];
    s0 += v.x; q0 = fmaf(v.x, v.x, q0);
    s1 += v.y; q1 = fmaf(v.y, v.y, q1);
  }
  float mu0 = s0 * (1.f / 64.f), mu1 = s1 * (1.f / 64.f);
  float4 r;
  r.x = mu0; r.y = rsqrtf(fmaf(-mu0, mu0, q0 * (1.f / 64.f)) + 1e-5f);
  r.z = mu1; r.w = rsqrtf(fmaf(-mu1, mu1, q1 * (1.f / 64.f)) + 1e-5f);
  stats4[id] = r;
}

// ---------------- K1: LN apply -> xn fp16 (t-innermost) -------------------
// xn: [bc][px][8 words], word tp = (t=2tp, t=2tp+1). Thread = px-pair.
__global__ __launch_bounds__(256) void k_xn(
    const float2* __restrict__ x2, const float4* __restrict__ stats4,
    const float* __restrict__ lnw, const float* __restrict__ lnb,
    unsigned int* __restrict__ xnw) {
  int bc = blockIdx.y, bt = bc >> 6, ci = bc & 63;
  int jp = blockIdx.x * 256 + threadIdx.x;   // px-pair [0,8192)
  float lw = lnw[ci], lb = lnb[ci];
  unsigned int w0[8], w1[8];
#pragma unroll
  for (int tp = 0; tp < 8; ++tp) {
    int bb0 = (bt << 4) + 2 * tp;
    float2 xa = x2[(((size_t)((bb0 << 6) + ci)) << 13) + jp];
    float2 xb = x2[(((size_t)(((bb0 + 1) << 6) + ci)) << 13) + jp];
    float4 sa = stats4[((size_t)bb0 << 13) + jp];
    float4 sb = stats4[((size_t)(bb0 + 1) << 13) + jp];
    w0[tp] = f2h2(fmaf((xa.x - sa.x) * sa.y, lw, lb),
                  fmaf((xb.x - sb.x) * sb.y, lw, lb));
    w1[tp] = f2h2(fmaf((xa.y - sa.z) * sa.w, lw, lb),
                  fmaf((xb.y - sb.z) * sb.w, lw, lb));
  }
  size_t base = (((size_t)bc << 14) + 2 * (size_t)jp) * 8;
  *reinterpret_cast<uint4*>(&xnw[base + 0]) = make_uint4(w0[0], w0[1], w0[2], w0[3]);
  *reinterpret_cast<uint4*>(&xnw[base + 4]) = make_uint4(w0[4], w0[5], w0[6], w0[7]);
  *reinterpret_cast<uint4*>(&xnw[base + 8]) = make_uint4(w1[0], w1[1], w1[2], w1[3]);
  *reinterpret_cast<uint4*>(&xnw[base + 12]) = make_uint4(w1[4], w1[5], w1[6], w1[7]);
}

// ---------------- K2: global-fed MFMA 1x1 + dw3x3 + attn partials + v -----
__global__ __launch_bounds__(256) void k_fused(
    const unsigned int* __restrict__ xnw, const unsigned int* __restrict__ qkvpk,
    const unsigned int* __restrict__ dwpk, unsigned int* __restrict__ vbuf,
    float* __restrict__ Sacc, float* __restrict__ Nacc) {
  __shared__ unsigned int pre[8 * 612];   // 19.6 KB
  __shared__ unsigned int qk[16 * 258];   // 16.5 KB
  int tid = threadIdx.x;
  int bc = blockIdx.y;
  int tx0 = (blockIdx.x & 3) << 5;
  int ty0 = (blockIdx.x >> 2) << 4;
  int lane15 = tid & 15;
  int kg = (tid >> 4) & 3;
  int wv = tid >> 6;
  int iy = tid >> 4, jx = tid & 15;
  int dwbase = iy * 34 + 2 * jx;

  uint4 bfr[10];
#pragma unroll
  for (int i = 0; i < 10; ++i) {
    int hp = (wv + 4 * i) * 16 + lane15;
    int hy = hp / 34, hx = hp - hy * 34;
    int gy = ty0 + hy - 1, gx = tx0 + hx - 1;
    bool ok = (hp < 612) && ((unsigned)gy < 128u) && ((unsigned)gx < 128u);
    uint4 bw = make_uint4(0, 0, 0, 0);
    if (ok && kg < 2)
      bw = *reinterpret_cast<const uint4*>(
          &xnw[((size_t)bc << 17) + (size_t)((gy << 7) + gx) * 8 + 4 * kg]);
    bfr[i] = bw;
  }

  for (int m = 0; m < 3; ++m) {
    if (m > 0) {
      int pm = m - 1;
      {
        int combo = tid >> 3, pc = tid & 7;
        int hp_ = combo >> 4, cd = combo & 15, cc = cd >> 2, dd = cd & 3;
        const unsigned int* qrow = qk + (4 * hp_ + cc) * 258;
        const unsigned int* krow = qk + (8 + 4 * hp_ + dd) * 258;
        float s = 0.f;
#pragma unroll
        for (int i = 0; i < 16; ++i) {
          uint2 q2 = *reinterpret_cast<const uint2*>(&qrow[2 * pc + (i << 4)]);
          uint2 k2 = *reinterpret_cast<const uint2*>(&krow[2 * pc + (i << 4)]);
          s = fdot2(q2.x, k2.x, s);
          s = fdot2(q2.y, k2.y, s);
        }
        s += __shfl_xor(s, 1); s += __shfl_xor(s, 2); s += __shfl_xor(s, 4);
        if (pc == 0)
          atomicAdd(&Sacc[((bc << 2) + 2 * pm + hp_) * 16 + cc * 4 + dd], s);
      }
      {
        int row = tid >> 4, pc = tid & 15;
        const unsigned int* rp = qk + row * 258;
        float n = 0.f;
#pragma unroll
        for (int i = 0; i < 8; ++i) {
          uint2 v2 = *reinterpret_cast<const uint2*>(&rp[2 * pc + (i << 5)]);
          n = fdot2(v2.x, v2.x, n);
          n = fdot2(v2.y, v2.y, n);
        }
        n += __shfl_xor(n, 1); n += __shfl_xor(n, 2);
        n += __shfl_xor(n, 4); n += __shfl_xor(n, 8);
        if (pc == 0) {
          int g = (row < 8) ? (8 * pm + row) : (16 + 8 * pm + (row - 8));
          atomicAdd(&Nacc[(bc << 5) + g], n);
        }
      }
    }
    {
      int gch = (m < 2)
                    ? ((lane15 < 8) ? (8 * m + lane15) : (16 + 8 * m + (lane15 - 8)))
                    : (32 + lane15);
      uint4 aw = make_uint4(0, 0, 0, 0);
      if (kg < 2) aw = *reinterpret_cast<const uint4*>(&qkvpk[gch * 8 + 4 * kg]);
      half8_t af = __builtin_bit_cast(half8_t, aw);
      float4_t zz = {0.f, 0.f, 0.f, 0.f};
#pragma unroll
      for (int i = 0; i < 10; ++i) {
        int hp = (wv + 4 * i) * 16 + lane15;
        half8_t bf = __builtin_bit_cast(half8_t, bfr[i]);
        float4_t d = __builtin_amdgcn_mfma_f32_16x16x32_f16(af, bf, zz, 0, 0, 0);
        if (hp < 612) {
          pre[(2 * kg) * 612 + hp] = f2h2(d[0], d[1]);
          pre[(2 * kg + 1) * 612 + hp] = f2h2(d[2], d[3]);
        }
      }
    }
    __syncthreads();
    unsigned int vs0[8], vs1[8];
#pragma unroll
    for (int pl = 0; pl < 8; ++pl) {
      int gpl = (m < 2) ? ((pl < 4) ? (4 * m + pl) : (8 + 4 * m + (pl - 4)))
                        : (16 + pl);
      const unsigned int* wp = dwpk + gpl * 9;
      __half2 a0 = __floats2half2_rn(0.f, 0.f), a1 = a0;
      int base = pl * 612 + dwbase;
#pragma unroll
      for (int dy = 0; dy < 3; ++dy) {
        uint2 A = *reinterpret_cast<const uint2*>(&pre[base + dy * 34]);
        uint2 B = *reinterpret_cast<const uint2*>(&pre[base + dy * 34 + 2]);
        __half2 d0 = __builtin_bit_cast(__half2, A.x);
        __half2 d1 = __builtin_bit_cast(__half2, A.y);
        __half2 d2 = __builtin_bit_cast(__half2, B.x);
        __half2 d3 = __builtin_bit_cast(__half2, B.y);
        __half2 w0 = __builtin_bit_cast(__half2, wp[dy * 3 + 0]);
        __half2 w1 = __builtin_bit_cast(__half2, wp[dy * 3 + 1]);
        __half2 w2 = __builtin_bit_cast(__half2, wp[dy * 3 + 2]);
        a0 = __hfma2(w0, d0, a0); a0 = __hfma2(w1, d1, a0); a0 = __hfma2(w2, d2, a0);
        a1 = __hfma2(w0, d1, a1); a1 = __hfma2(w1, d2, a1); a1 = __hfma2(w2, d3, a1);
      }
      unsigned int u0 = __builtin_bit_cast(unsigned int, a0);
      unsigned int u1 = __builtin_bit_cast(unsigned int, a1);
      if (m < 2) {
        qk[(2 * pl) * 258 + tid]     = (u0 & 0xFFFFu) | (u1 << 16);
        qk[(2 * pl + 1) * 258 + tid] = (u0 >> 16) | (u1 & 0xFFFF0000u);
      } else {
        vs0[pl] = u0;
        vs1[pl] = u1;
      }
    }
    if (m < 2) {
      __syncthreads();
    } else {
      int px0 = ((ty0 + iy) << 7) + tx0 + 2 * jx;
#pragma unroll
      for (int hg = 0; hg < 4; ++hg) {
        size_t a = (((size_t)(bc * 4 + hg)) << 15) + (size_t)px0 * 2;
        *reinterpret_cast<uint4*>(&vbuf[a]) =
            make_uint4(vs0[2 * hg], vs0[2 * hg + 1], vs1[2 * hg], vs1[2 * hg + 1]);
      }
    }
  }
}

// ---------------- K3: softmax + out = proj @ (attn . v), c-loop ----------
__global__ __launch_bounds__(256) void k_outproj(
    const unsigned int* __restrict__ vbuf, const float* __restrict__ Sacc,
    const float* __restrict__ Nacc, const float* __restrict__ temp,
    const unsigned int* __restrict__ projpk, float* __restrict__ out) {
  __shared__ unsigned int Yl[32 * 260];   // [ci2][px], stride 260
  __shared__ unsigned int attn_l[512];    // [c][ci][2]
  int tid = threadIdx.x;
  int comb = blockIdx.y;                  // bt*4 + hd
  int bt = comb >> 2, hd = comb & 3;
  int lane15 = tid & 15;
  int kg = (tid >> 4) & 3;
  int wv = tid >> 6;

  {  // all 4 c-rows of softmax: c = tid>>6, ci = tid&63
    int c = tid >> 6, ci = tid & 63;
    int b = (bt << 6) + ci;
    float tp = temp[hd];
    float iq = 1.f / fmaxf(sqrtf(Nacc[(b << 5) + (hd << 2) + c]), 1e-12f);
    float l[4];
#pragma unroll
    for (int d = 0; d < 4; ++d) {
      float ik = 1.f / fmaxf(sqrtf(Nacc[(b << 5) + 16 + (hd << 2) + d]), 1e-12f);
      l[d] = Sacc[((b << 2) + hd) * 16 + c * 4 + d] * iq * ik * tp;
    }
    float mx = fmaxf(fmaxf(l[0], l[1]), fmaxf(l[2], l[3]));
    float e0 = expf(l[0] - mx), e1 = expf(l[1] - mx);
    float e2 = expf(l[2] - mx), e3 = expf(l[3] - mx);
    float inv = 1.f / (e0 + e1 + e2 + e3);
    attn_l[c * 128 + 2 * ci] = f2h2(e0 * inv, e1 * inv);
    attn_l[c * 128 + 2 * ci + 1] = f2h2(e2 * inv, e3 * inv);
  }
  __syncthreads();

  half8_t A0[4], A1[4];
#pragma unroll
  for (int ot = 0; ot < 4; ++ot) {
    A0[ot] = __builtin_bit_cast(
        half8_t, *reinterpret_cast<const uint4*>(
                     &projpk[(ot * 16 + lane15) * 32 + kg * 4]));
    A1[ot] = __builtin_bit_cast(
        half8_t, *reinterpret_cast<const uint4*>(
                     &projpk[(ot * 16 + lane15) * 32 + 16 + kg * 4]));
  }
  float4_t zz = {0.f, 0.f, 0.f, 0.f};
  int gpx = (blockIdx.x << 8) + tid;
  size_t vb = (((size_t)(bt * 256 + hd)) << 15) + (size_t)gpx * 2;

  for (int c = 0; c < 4; ++c) {
    {
      const unsigned int* al = attn_l + c * 128;
#pragma unroll
      for (int ci2 = 0; ci2 < 32; ++ci2) {
        uint2 A0v = *reinterpret_cast<const uint2*>(&vbuf[vb + ((size_t)(2 * ci2) << 17)]);
        uint2 A1v = *reinterpret_cast<const uint2*>(&vbuf[vb + ((size_t)(2 * ci2 + 1) << 17)]);
        uint4 aw = *reinterpret_cast<const uint4*>(&al[4 * ci2]);
        float y0 = fdot2(A0v.x, aw.x, fdot2(A0v.y, aw.y, 0.f));
        float y1 = fdot2(A1v.x, aw.z, fdot2(A1v.y, aw.w, 0.f));
        Yl[ci2 * 260 + tid] = f2h2(y0, y1);
      }
    }
    __syncthreads();
    size_t outbase = ((size_t)((bt << 4) + (hd << 2) + c) << 20) + (blockIdx.x << 8);
#pragma unroll
    for (int pt = 0; pt < 4; ++pt) {
      int pxl = wv * 64 + pt * 16 + lane15;
      unsigned int r0 = Yl[(kg * 4 + 0) * 260 + pxl];
      unsigned int r1 = Yl[(kg * 4 + 1) * 260 + pxl];
      unsigned int r2 = Yl[(kg * 4 + 2) * 260 + pxl];
      unsigned int r3 = Yl[(kg * 4 + 3) * 260 + pxl];
      half8_t B0 = __builtin_bit_cast(half8_t, make_uint4(r0, r1, r2, r3));
      unsigned int s0 = Yl[(16 + kg * 4 + 0) * 260 + pxl];
      unsigned int s1 = Yl[(16 + kg * 4 + 1) * 260 + pxl];
      unsigned int s2 = Yl[(16 + kg * 4 + 2) * 260 + pxl];
      unsigned int s3 = Yl[(16 + kg * 4 + 3) * 260 + pxl];
      half8_t B1 = __builtin_bit_cast(half8_t, make_uint4(s0, s1, s2, s3));
#pragma unroll
      for (int ot = 0; ot < 4; ++ot) {
        float4_t d = __builtin_amdgcn_mfma_f32_16x16x32_f16(A0[ot], B0, zz, 0, 0, 0);
        d = __builtin_amdgcn_mfma_f32_16x16x32_f16(A1[ot], B1, d, 0, 0, 0);
        int o0 = ot * 16 + kg * 4;
#pragma unroll
        for (int r = 0; r < 4; ++r)
          out[outbase + ((size_t)(o0 + r) << 14) + pxl] = d[r];
      }
    }
    __syncthreads();
  }
}

extern "C" void kernel_launch(void* const* d_in, const int* in_sizes, int n_in,
                              void* d_out, int out_size, void* d_ws, size_t ws_size,
                              hipStream_t stream) {
  const float* x = (const float*)d_in[0];
  const float* lnw = (const float*)d_in[1];
  const float* lnb = (const float*)d_in[2];
  const float* qkvw = (const float*)d_in[3];
  const float* dww = (const float*)d_in[4];
  const float* projw = (const float*)d_in[5];
  const float* temp = (const float*)d_in[6];
  float* out = (float*)d_out;

  // workspace: xn 64 MiB | vbuf 64 MiB | stats 4 MiB | Sacc | Nacc | packs
  unsigned int* xnw = (unsigned int*)d_ws;
  unsigned int* vbuf = xnw + (67108864ull / 4);
  char* tail = (char*)d_ws + 134217728ull;
  float4* stats4 = (float4*)tail;                         // 4 MiB
  float* Sacc = (float*)(tail + 4194304ull);              // 8192 f32
  float* Nacc = Sacc + 8192;                              // 4096 f32
  unsigned int* projpk = (unsigned int*)(Nacc + 4096);    // 2048 u32
  unsigned int* qkvpk = projpk + 2048;                    // 384 u32
  unsigned int* dwpk = qkvpk + 384;                       // 216 u32

  k_stats<<<dim3(1025), dim3(256), 0, stream>>>((const float2*)x, stats4, qkvw,
                                                dww, projw, qkvpk, dwpk, projpk,
                                                Sacc);
  k_xn<<<dim3(32, 128), dim3(256), 0, stream>>>((const float2*)x, stats4, lnw,
                                                lnb, xnw);
  k_fused<<<dim3(32, 128), dim3(256), 0, stream>>>(xnw, qkvpk, dwpk, vbuf, Sacc,
                                                   Nacc);
  k_outproj<<<dim3(64, 8), dim3(256), 0, stream>>>(vbuf, Sacc, Nacc, temp,
                                                   projpk, out);
}